// Round 10
// baseline (348.614 us; speedup 1.0000x reference)
//
#include <hip/hip_runtime.h>
#include <hip/hip_bf16.h>
#include <stdint.h>

typedef __hip_bfloat16 bf16;
using f32x4 = __attribute__((ext_vector_type(4))) float;
using s16x8 = __attribute__((ext_vector_type(8))) short;

typedef __attribute__((address_space(1))) unsigned int gu32;
typedef __attribute__((address_space(3))) unsigned int lu32;

__device__ __forceinline__ void gll16(const void* g, void* l) {
  __builtin_amdgcn_global_load_lds((const gu32*)g, (lu32*)l, 16, 0, 0);
}

// ---------------- convert f32 -> bf16 ----------------
struct ConvJob { const float* src; bf16* dst; int n4; int pad; };
struct ConvParams { ConvJob j[10]; };
struct alignas(8) Bf4 { bf16 v[4]; };

__global__ void convert_kernel(ConvParams p) {
  ConvJob jb = p.j[blockIdx.z];
  int stride = gridDim.x * blockDim.x;
  for (int i = blockIdx.x * blockDim.x + threadIdx.x; i < jb.n4; i += stride) {
    float4 v = ((const float4*)jb.src)[i];
    Bf4 o;
    o.v[0] = __float2bfloat16(v.x);
    o.v[1] = __float2bfloat16(v.y);
    o.v[2] = __float2bfloat16(v.z);
    o.v[3] = __float2bfloat16(v.w);
    ((Bf4*)jb.dst)[i] = o;
  }
}

// ---------------- GEMM: C = A(MxK) @ W(NxK)^T + bias ----------------
// K-loop: round-1 verified structure (128x128 tile, 256 thr, 4 waves 2x2,
// dbuf 64 KiB, counted vmcnt(8), T2 swizzle, setprio). Epilogue (round 6,
// verified win): per-wave padded LDS transpose buffer -> 128-B coalesced
// global writes instead of 64 scattered 2-B stores.
struct GemmSlice {
  const bf16* A; const bf16* W; const float* bias;
  bf16* dstQ; float* dstF;
  long lda; int dhalf; float scale; int mode;
};
struct GemmParams { GemmSlice s[6]; };

// per wave: 4 A-loads + 4 B-loads = 8 gll16 per tile
#define GSTAGE(kb, bA, bB) do { \
    _Pragma("unroll") \
    for (int i_ = 0; i_ < 4; ++i_) { \
      const int r0_ = w * 32 + i_ * 8; \
      gll16(Abase + (long)r0_ * lda + (kb) * 64, (bA) + r0_ * 64); \
      gll16(Wbase + (long)r0_ * 512 + (kb) * 64, (bB) + r0_ * 64); \
    } \
  } while (0)

#define GCOMPUTE(bA, bB) do { \
  _Pragma("unroll") \
  for (int ks = 0; ks < 2; ++ks) { \
    s16x8 af[4], bg[4]; \
    _Pragma("unroll") \
    for (int mi = 0; mi < 4; ++mi) { \
      const int row_ = wm + mi * 16 + fr; \
      af[mi] = *(const s16x8*)((bA) + row_ * 64 + ((ks * 32 + fq * 8) ^ ((row_ & 7) << 3))); \
    } \
    _Pragma("unroll") \
    for (int ni = 0; ni < 4; ++ni) { \
      const int row_ = wn + ni * 16 + fr; \
      bg[ni] = *(const s16x8*)((bB) + row_ * 64 + ((ks * 32 + fq * 8) ^ ((row_ & 7) << 3))); \
    } \
    __builtin_amdgcn_s_setprio(1); \
    _Pragma("unroll") \
    for (int mi = 0; mi < 4; ++mi) \
      _Pragma("unroll") \
      for (int ni = 0; ni < 4; ++ni) \
        acc[mi][ni] = __builtin_amdgcn_mfma_f32_16x16x32_bf16(af[mi], bg[ni], acc[mi][ni], 0, 0, 0); \
    __builtin_amdgcn_s_setprio(0); \
  } \
} while (0)

__global__ __launch_bounds__(256, 2) void gemm_kernel(GemmParams p) {
  __shared__ alignas(16) bf16 lds[4 * 8192];   // 64 KiB: sA0,sB0,sA1,sB1
  bf16* const sA0 = lds;
  bf16* const sB0 = lds + 8192;
  bf16* const sA1 = lds + 16384;
  bf16* const sB1 = lds + 24576;
  const GemmSlice sl = p.s[blockIdx.z];
  const long lda = sl.lda;
  const int tid = threadIdx.x;
  const int w = tid >> 6, ln = tid & 63;
  const int gm0 = blockIdx.x * 128;
  const int gn0 = blockIdx.y * 128;
  const int arow = ln >> 3;
  const int acolS = ((ln & 7) ^ (ln >> 3)) * 8;   // inverse-swizzled source column
  const int wm = (w >> 1) * 64, wn = (w & 1) * 64;
  const int fr = ln & 15, fq = ln >> 4;
  const bf16* const Abase = sl.A + (long)(gm0 + arow) * lda + acolS;
  const bf16* const Wbase = sl.W + (long)(gn0 + arow) * 512 + acolS;
  f32x4 acc[4][4] = {};

  GSTAGE(0, sA0, sB0);
  GSTAGE(1, sA1, sB1);

  for (int kt = 0; kt < 7; ++kt) {
    bf16* const bA = (kt & 1) ? sA1 : sA0;
    bf16* const bB = (kt & 1) ? sB1 : sB0;
    asm volatile("s_waitcnt vmcnt(8)" ::: "memory");   // tile kt landed; kt+1 in flight
    __builtin_amdgcn_sched_barrier(0);
    __builtin_amdgcn_s_barrier();
    GCOMPUTE(bA, bB);
    asm volatile("s_waitcnt lgkmcnt(0)" ::: "memory"); // my LDS reads complete
    __builtin_amdgcn_sched_barrier(0);
    __builtin_amdgcn_s_barrier();                      // everyone done reading buf
    if (kt < 6) GSTAGE(kt + 2, bA, bB);                // overwrite current buf
  }
  asm volatile("s_waitcnt vmcnt(0)" ::: "memory");
  __builtin_amdgcn_sched_barrier(0);
  __builtin_amdgcn_s_barrier();
  GCOMPUTE(sA1, sB1);   // tile 7

  // all waves done reading staging LDS before epilogue overwrites it
  asm volatile("s_waitcnt lgkmcnt(0)" ::: "memory");
  __builtin_amdgcn_sched_barrier(0);
  __builtin_amdgcn_s_barrier();

  // --- coalesced epilogue via per-wave LDS transpose buffer (64x72 bf16) ---
  bf16* const eW = lds + w * 4608;          // 9216 B/wave, 36,864 B total
  if (sl.mode == 0) {
    const int col0 = gn0 + wn;              // 64-aligned -> single head h
    const int h = col0 >> 6;
    const int bh = ((gm0 >> 9) << 3) + h;
    const int tb = (gm0 & 511) + wm;
#pragma unroll
    for (int ni = 0; ni < 4; ++ni) {
      const float bia = sl.bias[col0 + ni * 16 + fr];
#pragma unroll
      for (int mi = 0; mi < 4; ++mi)
#pragma unroll
        for (int r = 0; r < 4; ++r)
          eW[(mi * 16 + fq * 4 + r) * 72 + ni * 16 + fr] =
              __float2bfloat16((acc[mi][ni][r] + bia) * sl.scale);
    }
#pragma unroll
    for (int pp = 0; pp < 8; ++pp) {
      const int rr = pp * 8 + (ln >> 3);
      const s16x8 v = *(const s16x8*)(eW + rr * 72 + (ln & 7) * 8);
      *(s16x8*)(sl.dstQ + (((long)bh * 512 + tb + rr) << 7) + sl.dhalf + (ln & 7) * 8) = v;
    }
  } else if (sl.mode == 2) {
    const int col0 = gn0 + wn;
    const int h = col0 >> 6;
    const int bh = ((gm0 >> 9) << 3) + h;
    const int tb = (gm0 & 511) + wm;
    // LDS layout [dd 0..63][t 0..63 pad 72]; acc r-values are t-contiguous
#pragma unroll
    for (int ni = 0; ni < 4; ++ni) {
      const float bia = sl.bias[col0 + ni * 16 + fr];
#pragma unroll
      for (int mi = 0; mi < 4; ++mi) {
        Bf4 o;
#pragma unroll
        for (int r = 0; r < 4; ++r) o.v[r] = __float2bfloat16(acc[mi][ni][r] + bia);
        *(Bf4*)(eW + (ni * 16 + fr) * 72 + mi * 16 + fq * 4) = o;
      }
    }
#pragma unroll
    for (int pp = 0; pp < 8; ++pp) {
      const int rr = pp * 8 + (ln >> 3);   // dd index within wave tile
      const s16x8 v = *(const s16x8*)(eW + rr * 72 + (ln & 7) * 8);
      *(s16x8*)(sl.dstQ + (((long)bh * 128 + sl.dhalf + rr) << 9) + tb + (ln & 7) * 8) = v;
    }
  } else {
#pragma unroll
    for (int mi = 0; mi < 4; ++mi)
#pragma unroll
      for (int ni = 0; ni < 4; ++ni) {
        const int col = gn0 + wn + ni * 16 + fr;
        const float bia = sl.bias[col];
#pragma unroll
        for (int r = 0; r < 4; ++r) {
          const int row = gm0 + wm + mi * 16 + fq * 4 + r;
          sl.dstF[(long)row * 512 + col] = acc[mi][ni][r] + bia;
        }
      }
  }
}

// ---------------- flash attention (4-wave, single KV buffer + T14 reg-staging) ----------------
// Round-6 structure, occupancy-lifted: LDS 48 KiB (K 16 + V 16 + sP 16)
// -> 3 blocks/CU = 12 waves/CU = 3 waves/SIMD (was 2). Next tile staged
// global->reg BEFORE COMPUTE (HBM/L2 latency hides under MFMA), written
// reg->LDS after the post-COMPUTE barrier (T14). Prologue tile 0 via gll16.
// 2 barriers/tile as before. Q pre-scaled by log2e/8; no running max.
// Epilogue: coalesced AO write via freed sPw (rounds 7/8 verified).
#define STAGE(kt) do { \
    _Pragma("unroll") \
    for (int p_ = 0; p_ < 4; ++p_) \
      gll16(kgb + (kt) * 8192 + p_ * 2048, ldsK + tid * 8 + p_ * 2048); \
    _Pragma("unroll") \
    for (int p_ = 0; p_ < 4; ++p_) \
      gll16(vgb + (kt) * 64 + p_ * 16384, ldsV + tid * 8 + p_ * 2048); \
  } while (0)

#define LOADR(kt) do { \
    _Pragma("unroll") \
    for (int p_ = 0; p_ < 4; ++p_) kreg[p_] = *(const s16x8*)(kgb + (kt) * 8192 + p_ * 2048); \
    _Pragma("unroll") \
    for (int p_ = 0; p_ < 4; ++p_) vreg[p_] = *(const s16x8*)(vgb + (kt) * 64 + p_ * 16384); \
  } while (0)

#define WRITER() do { \
    _Pragma("unroll") \
    for (int p_ = 0; p_ < 4; ++p_) *(s16x8*)(ldsK + tid * 8 + p_ * 2048) = kreg[p_]; \
    _Pragma("unroll") \
    for (int p_ = 0; p_ < 4; ++p_) *(s16x8*)(ldsV + tid * 8 + p_ * 2048) = vreg[p_]; \
  } while (0)

#define COMPUTE() do { \
  f32x4 s2[2][4] = {}; \
  _Pragma("unroll") \
  for (int ks = 0; ks < 4; ++ks) { \
    _Pragma("unroll") \
    for (int ni = 0; ni < 4; ++ni) { \
      const int row_ = ni * 16 + fr; \
      const s16x8 kf = *(const s16x8*)(ldsK + row_ * 128 + ((ks * 32 + fq * 8) ^ ((row_ & 7) << 3))); \
      _Pragma("unroll") \
      for (int mi = 0; mi < 2; ++mi) \
        s2[mi][ni] = __builtin_amdgcn_mfma_f32_16x16x32_bf16(qf[mi][ks], kf, s2[mi][ni], 0, 0, 0); \
    } \
  } \
  _Pragma("unroll") \
  for (int mi = 0; mi < 2; ++mi) \
    _Pragma("unroll") \
    for (int r = 0; r < 4; ++r) { \
      float ps = 0.f; \
      _Pragma("unroll") \
      for (int ni = 0; ni < 4; ++ni) { \
        const float pe = __builtin_amdgcn_exp2f(s2[mi][ni][r]); \
        s2[mi][ni][r] = pe; ps += pe; \
      } \
      ps += __shfl_xor(ps, 1); ps += __shfl_xor(ps, 2); \
      ps += __shfl_xor(ps, 4); ps += __shfl_xor(ps, 8); \
      lrow[mi][r] += ps; \
    } \
  _Pragma("unroll") \
  for (int mi = 0; mi < 2; ++mi) \
    _Pragma("unroll") \
    for (int ni = 0; ni < 4; ++ni) \
      _Pragma("unroll") \
      for (int r = 0; r < 4; ++r) { \
        const int rp = mi * 16 + fq * 4 + r; \
        sPw[rp * 64 + ((ni * 16 + fr) ^ ((rp & 7) << 3))] = __float2bfloat16(s2[mi][ni][r]); \
      } \
  _Pragma("unroll") \
  for (int ks = 0; ks < 2; ++ks) { \
    s16x8 pf[2]; \
    _Pragma("unroll") \
    for (int mi = 0; mi < 2; ++mi) { \
      const int row_ = mi * 16 + fr; \
      pf[mi] = *(const s16x8*)(sPw + row_ * 64 + ((ks * 32 + fq * 8) ^ ((row_ & 7) << 3))); \
    } \
    _Pragma("unroll") \
    for (int nj = 0; nj < 8; ++nj) { \
      const int row_ = nj * 16 + fr; \
      const s16x8 vf = *(const s16x8*)(ldsV + row_ * 64 + ((ks * 32 + fq * 8) ^ ((row_ & 7) << 3))); \
      _Pragma("unroll") \
      for (int mi = 0; mi < 2; ++mi) \
        o[mi][nj] = __builtin_amdgcn_mfma_f32_16x16x32_bf16(pf[mi], vf, o[mi][nj], 0, 0, 0); \
    } \
  } \
} while (0)

__global__ __launch_bounds__(256, 3) void attn_kernel(const bf16* __restrict__ Q,
                                                      const bf16* __restrict__ K,
                                                      const bf16* __restrict__ Vt,
                                                      bf16* __restrict__ AO) {
  __shared__ alignas(16) bf16 lds[24576];   // 48 KiB: K 16 + V 16 + sP 16
  bf16* const ldsK = lds;                   // [64][128]
  bf16* const ldsV = lds + 8192;            // [128][64]
  bf16* const sP   = lds + 16384;           // 4 waves x [32][64]
  const int tid = threadIdx.x;
  const int w = tid >> 6, ln = tid & 63;
  const int fr = ln & 15, fq = ln >> 4;
  const int lg = (blockIdx.x & 7) * 128 + (blockIdx.x >> 3);
  const int bh = lg >> 2;
  const int q0 = (lg & 3) * 128;
  const long base = (long)bh << 16;         // bh * 512 * 128
  bf16* const sPw = sP + w * 2048;

  // thread-constant staging source bases (inverse-swizzled global addresses)
  const int kr0 = tid >> 4, kc = tid & 15;          // K/Q chunk coords
  const int vr0 = tid >> 3, vc = tid & 7;           // V^T chunk coords
  const bf16* const kgb = K + base + kr0 * 128 + ((kc ^ (kr0 & 7)) * 8);
  const bf16* const vgb = Vt + base + (long)vr0 * 512 + ((vc ^ (vr0 & 7)) * 8);

  // --- stage Q tile (128x128) swizzled into lds[0..16383], read fragments
  {
    const bf16* const qgb = Q + base + (long)q0 * 128 + kr0 * 128 + ((kc ^ (kr0 & 7)) * 8);
#pragma unroll
    for (int p = 0; p < 8; ++p)
      gll16(qgb + p * 2048, lds + tid * 8 + p * 2048);
  }
  __syncthreads();   // drains vmcnt(0): Q landed for all waves
  s16x8 qf[2][4];
#pragma unroll
  for (int mi = 0; mi < 2; ++mi) {
    const int row = w * 32 + mi * 16 + fr;
#pragma unroll
    for (int ks = 0; ks < 4; ++ks)
      qf[mi][ks] = *(const s16x8*)(lds + row * 128 + ((ks * 32 + fq * 8) ^ ((row & 7) << 3)));
  }
  __syncthreads();   // drains lgkm: Q region free for tile0

  f32x4 o[2][8] = {};
  float lrow[2][4] = {};
  s16x8 kreg[4], vreg[4];

  STAGE(0);                                  // tile 0 -> LDS via gll16
  __builtin_amdgcn_sched_barrier(0);
  LOADR(1);                                  // tile 1 -> regs (latency hides)
  __builtin_amdgcn_sched_barrier(0);
  asm volatile("s_waitcnt vmcnt(8)" ::: "memory");   // tile 0 landed (8 reg loads outstanding)
  __builtin_amdgcn_sched_barrier(0);
  __builtin_amdgcn_s_barrier();

  for (int kt = 0; kt < 8; ++kt) {
    COMPUTE();                               // tile kt from LDS
    asm volatile("s_waitcnt lgkmcnt(0)" ::: "memory"); // my LDS reads complete
    __builtin_amdgcn_sched_barrier(0);
    __builtin_amdgcn_s_barrier();            // everyone done reading tile kt
    if (kt < 7) {
      WRITER();                              // regs (tile kt+1) -> LDS; compiler waits vmcnt
      if (kt < 6) LOADR(kt + 2);             // issue next reg loads (hide under next COMPUTE)
      asm volatile("s_waitcnt lgkmcnt(0)" ::: "memory"); // my LDS writes complete
      __builtin_amdgcn_sched_barrier(0);
      __builtin_amdgcn_s_barrier();          // all writes visible
    }
  }

  // --- epilogue: O /= l; coalesced AO writes via freed sPw ---
  const int b = bh >> 3, h = bh & 7;
  float rl[2][4];
#pragma unroll
  for (int mi = 0; mi < 2; ++mi)
#pragma unroll
    for (int r = 0; r < 4; ++r) rl[mi][r] = 1.f / lrow[mi][r];
#pragma unroll
  for (int hh = 0; hh < 2; ++hh) {
#pragma unroll
    for (int mi = 0; mi < 2; ++mi)
#pragma unroll
      for (int nj4 = 0; nj4 < 4; ++nj4)
#pragma unroll
        for (int r = 0; r < 4; ++r) {
          const int rp = mi * 16 + fq * 4 + r;
          sPw[rp * 64 + ((nj4 * 16 + fr) ^ ((rp & 7) << 3))] =
              __float2bfloat16(o[mi][hh * 4 + nj4][r] * rl[mi][r]);
        }
#pragma unroll
    for (int pp = 0; pp < 4; ++pp) {
      const int rr = pp * 8 + (ln >> 3);
      const s16x8 v = *(const s16x8*)(sPw + rr * 64 + (((ln & 7) * 8) ^ ((rr & 7) << 3)));
      *(s16x8*)(AO + (((long)(b * 512 + q0 + w * 32 + rr)) << 10) + h * 128 + hh * 64 + (ln & 7) * 8) = v;
    }
  }
}

// ---------------- launch ----------------
extern "C" void kernel_launch(void* const* d_in, const int* in_sizes, int n_in,
                              void* d_out, int out_size, void* d_ws, size_t ws_size,
                              hipStream_t stream) {
  const float* xf = (const float*)d_in[0];
  const float* xs = (const float*)d_in[1];
  // weight order in WW: 0=wq1,1=wk1,2=wv1,3=wq2,4=wk2,5=wv2,6=wo1,7=wo2
  const float* w_f[8] = { (const float*)d_in[2], (const float*)d_in[4], (const float*)d_in[6],
                          (const float*)d_in[8], (const float*)d_in[10], (const float*)d_in[12],
                          (const float*)d_in[14], (const float*)d_in[16] };

  bf16* ws = (bf16*)d_ws;
  bf16* XF = ws;                       // 8,388,608 bf16
  bf16* XS = ws + 8388608;             // 8,388,608
  bf16* WW = ws + 16777216;            // 8 x 262,144
  bf16* Qb = ws + 18874368;            // 16,777,216 each
  bf16* Kb = Qb + 16777216;
  bf16* Vb = Kb + 16777216;            // V^T layout (bh, d, t)
  bf16* AO = ws;                       // reuse XF+XS region

  ConvParams cp;
  cp.j[0] = { xf, XF, 2097152, 0 };
  cp.j[1] = { xs, XS, 2097152, 0 };
  for (int i = 0; i < 8; ++i) cp.j[2 + i] = { w_f[i], WW + i * 262144, 65536, 0 };
  convert_kernel<<<dim3(512, 1, 10), 256, 0, stream>>>(cp);

  const float qsc = 0.125f * 1.44269504088896f;   // fold log2(e) so attn uses exp2
  GemmParams gp;
  gp.s[0] = { XF, WW + 0 * 262144, (const float*)d_in[3],  Qb, nullptr, 512, 0,  qsc, 0 };
  gp.s[1] = { XS, WW + 3 * 262144, (const float*)d_in[9],  Qb, nullptr, 512, 64, qsc, 0 };
  gp.s[2] = { XF, WW + 1 * 262144, (const float*)d_in[5],  Kb, nullptr, 512, 0,  1.f, 0 };
  gp.s[3] = { XS, WW + 4 * 262144, (const float*)d_in[11], Kb, nullptr, 512, 64, 1.f, 0 };
  gp.s[4] = { XF, WW + 2 * 262144, (const float*)d_in[7],  Vb, nullptr, 512, 0,  1.f, 2 };
  gp.s[5] = { XS, WW + 5 * 262144, (const float*)d_in[13], Vb, nullptr, 512, 64, 1.f, 2 };
  gemm_kernel<<<dim3(128, 4, 6), 256, 0, stream>>>(gp);

  attn_kernel<<<dim3(1024), 256, 0, stream>>>(Qb, Kb, Vb, AO);

  float* out = (float*)d_out;
  GemmParams op;
  op.s[0] = { AO,       WW + 6 * 262144, (const float*)d_in[15], nullptr, out,           1024, 0, 1.f, 1 };
  op.s[1] = { AO + 512, WW + 7 * 262144, (const float*)d_in[17], nullptr, out + 8388608, 1024, 0, 1.f, 1 };
  op.s[2] = op.s[0]; op.s[3] = op.s[0]; op.s[4] = op.s[0]; op.s[5] = op.s[0];
  gemm_kernel<<<dim3(128, 4, 2), 256, 0, stream>>>(op);
}

// Round 12
// 163.421 us; speedup vs baseline: 2.1332x; 2.1332x over previous
//
#include <hip/hip_runtime.h>
#include <hip/hip_bf16.h>
#include <stdint.h>

typedef __hip_bfloat16 bf16;
using f32x4 = __attribute__((ext_vector_type(4))) float;
using s16x8 = __attribute__((ext_vector_type(8))) short;

typedef __attribute__((address_space(1))) unsigned int gu32;
typedef __attribute__((address_space(3))) unsigned int lu32;

__device__ __forceinline__ void gll16(const void* g, void* l) {
  __builtin_amdgcn_global_load_lds((const gu32*)g, (lu32*)l, 16, 0, 0);
}

// ---------------- convert f32 -> bf16 ----------------
struct ConvJob { const float* src; bf16* dst; int n4; int pad; };
struct ConvParams { ConvJob j[10]; };
struct alignas(8) Bf4 { bf16 v[4]; };

__global__ void convert_kernel(ConvParams p) {
  ConvJob jb = p.j[blockIdx.z];
  int stride = gridDim.x * blockDim.x;
  for (int i = blockIdx.x * blockDim.x + threadIdx.x; i < jb.n4; i += stride) {
    float4 v = ((const float4*)jb.src)[i];
    Bf4 o;
    o.v[0] = __float2bfloat16(v.x);
    o.v[1] = __float2bfloat16(v.y);
    o.v[2] = __float2bfloat16(v.z);
    o.v[3] = __float2bfloat16(v.w);
    ((Bf4*)jb.dst)[i] = o;
  }
}

// ---------------- GEMM: C = A(MxK) @ W(NxK)^T + bias ----------------
// Occupancy experiment (round-11 rerun; nkt bug fixed): single-buffer
// 32 KiB K-loop (round-0 skeleton + round-1 T2 swizzle) so register state
// (VGPR ~60 + AGPR 64 = 124) and LDS both fit 4 blocks/CU at
// __launch_bounds__(256,4). K is ALWAYS 512 (8 tiles): lda=1024 for the
// out-proj is only A's ROW STRIDE (AO holds both halves), not the
// reduction depth — round-11's nkt=16 read the wrong half (absmax 4.8e-2).
// Epilogue: round-6 verified coalesced write, two 32-row passes in a
// wave-PRIVATE 4.5 KiB LDS buffer (no barriers, fits 32 KiB).
struct GemmSlice {
  const bf16* A; const bf16* W; const float* bias;
  bf16* dstQ; float* dstF;
  long lda; int dhalf; float scale; int mode;
};
struct GemmParams { GemmSlice s[6]; };

// per wave: 4 A-loads + 4 B-loads = 8 gll16 per tile
#define GSTAGE(kb) do { \
    _Pragma("unroll") \
    for (int i_ = 0; i_ < 4; ++i_) { \
      const int r0_ = w * 32 + i_ * 8; \
      gll16(Abase + (long)r0_ * lda + (kb) * 64, sA + r0_ * 64); \
      gll16(Wbase + (long)r0_ * 512 + (kb) * 64, sB + r0_ * 64); \
    } \
  } while (0)

#define GCOMPUTE() do { \
  _Pragma("unroll") \
  for (int ks = 0; ks < 2; ++ks) { \
    s16x8 af[4], bg[4]; \
    _Pragma("unroll") \
    for (int mi = 0; mi < 4; ++mi) { \
      const int row_ = wm + mi * 16 + fr; \
      af[mi] = *(const s16x8*)(sA + row_ * 64 + ((ks * 32 + fq * 8) ^ ((row_ & 7) << 3))); \
    } \
    _Pragma("unroll") \
    for (int ni = 0; ni < 4; ++ni) { \
      const int row_ = wn + ni * 16 + fr; \
      bg[ni] = *(const s16x8*)(sB + row_ * 64 + ((ks * 32 + fq * 8) ^ ((row_ & 7) << 3))); \
    } \
    __builtin_amdgcn_s_setprio(1); \
    _Pragma("unroll") \
    for (int mi = 0; mi < 4; ++mi) \
      _Pragma("unroll") \
      for (int ni = 0; ni < 4; ++ni) \
        acc[mi][ni] = __builtin_amdgcn_mfma_f32_16x16x32_bf16(af[mi], bg[ni], acc[mi][ni], 0, 0, 0); \
    __builtin_amdgcn_s_setprio(0); \
  } \
} while (0)

__global__ __launch_bounds__(256, 4) void gemm_kernel(GemmParams p) {
  __shared__ alignas(16) bf16 lds[16384];   // 32 KiB: sA @0, sB @8192
  bf16* const sA = lds;
  bf16* const sB = lds + 8192;
  const GemmSlice sl = p.s[blockIdx.z];
  const long lda = sl.lda;
  const int tid = threadIdx.x;
  const int w = tid >> 6, ln = tid & 63;
  const int gm0 = blockIdx.x * 128;
  const int gn0 = blockIdx.y * 128;
  const int arow = ln >> 3;
  const int acolS = ((ln & 7) ^ (ln >> 3)) * 8;   // inverse-swizzled source column
  const int wm = (w >> 1) * 64, wn = (w & 1) * 64;
  const int fr = ln & 15, fq = ln >> 4;
  const bf16* const Abase = sl.A + (long)(gm0 + arow) * lda + acolS;
  const bf16* const Wbase = sl.W + (long)(gn0 + arow) * 512 + acolS;
  f32x4 acc[4][4] = {};

  for (int kb = 0; kb < 8; ++kb) {   // K = 512 always (lda is only A's row stride)
    GSTAGE(kb);
    __syncthreads();   // drains vmcnt(0): tile landed
    GCOMPUTE();
    __syncthreads();   // all reads done before next-tile overwrite
  }

  // --- coalesced epilogue: wave-PRIVATE 32x72 buffer, two passes, no barriers ---
  bf16* const eW = lds + w * 2304;          // 4608 B/wave, 18,432 B total
  if (sl.mode == 0) {
    const int col0 = gn0 + wn;              // 64-aligned -> single head h
    const int h = col0 >> 6;
    const int bh = ((gm0 >> 9) << 3) + h;
    const int tb = (gm0 & 511) + wm;
#pragma unroll
    for (int ps = 0; ps < 2; ++ps) {        // rows mi = 2ps, 2ps+1
#pragma unroll
      for (int mi2 = 0; mi2 < 2; ++mi2) {
        const int mi = ps * 2 + mi2;
#pragma unroll
        for (int ni = 0; ni < 4; ++ni) {
          const float bia = sl.bias[col0 + ni * 16 + fr];
#pragma unroll
          for (int r = 0; r < 4; ++r)
            eW[(mi2 * 16 + fq * 4 + r) * 72 + ni * 16 + fr] =
                __float2bfloat16((acc[mi][ni][r] + bia) * sl.scale);
        }
      }
#pragma unroll
      for (int pp = 0; pp < 4; ++pp) {
        const int rr = pp * 8 + (ln >> 3);  // 0..31
        const s16x8 v = *(const s16x8*)(eW + rr * 72 + (ln & 7) * 8);
        *(s16x8*)(sl.dstQ + (((long)bh * 512 + tb + ps * 32 + rr) << 7) + sl.dhalf + (ln & 7) * 8) = v;
      }
    }
  } else if (sl.mode == 2) {
    const int col0 = gn0 + wn;
    const int h = col0 >> 6;
    const int bh = ((gm0 >> 9) << 3) + h;
    const int tb = (gm0 & 511) + wm;
    // eW layout per pass: [dd' 0..31][t 0..63 pad 72]
#pragma unroll
    for (int ps = 0; ps < 2; ++ps) {        // dd halves: ni = 2ps, 2ps+1
#pragma unroll
      for (int ni2 = 0; ni2 < 2; ++ni2) {
        const int ni = ps * 2 + ni2;
        const float bia = sl.bias[col0 + ni * 16 + fr];
#pragma unroll
        for (int mi = 0; mi < 4; ++mi) {
          Bf4 o;
#pragma unroll
          for (int r = 0; r < 4; ++r) o.v[r] = __float2bfloat16(acc[mi][ni][r] + bia);
          *(Bf4*)(eW + (ni2 * 16 + fr) * 72 + mi * 16 + fq * 4) = o;
        }
      }
#pragma unroll
      for (int pp = 0; pp < 4; ++pp) {
        const int rr = pp * 8 + (ln >> 3);  // dd' 0..31
        const s16x8 v = *(const s16x8*)(eW + rr * 72 + (ln & 7) * 8);
        *(s16x8*)(sl.dstQ + (((long)bh * 128 + sl.dhalf + ps * 32 + rr) << 9) + tb + (ln & 7) * 8) = v;
      }
    }
  } else {
#pragma unroll
    for (int mi = 0; mi < 4; ++mi)
#pragma unroll
      for (int ni = 0; ni < 4; ++ni) {
        const int col = gn0 + wn + ni * 16 + fr;
        const float bia = sl.bias[col];
#pragma unroll
        for (int r = 0; r < 4; ++r) {
          const int row = gm0 + wm + mi * 16 + fq * 4 + r;
          sl.dstF[(long)row * 512 + col] = acc[mi][ni][r] + bia;
        }
      }
  }
}

// ---------------- flash attention (round-6 verified structure + coalesced AO) ----------------
// 4 waves x 32 q-rows, KVBLK=64, dbuf gll16 + counted vmcnt(8), T2 swizzle.
// 80 KiB LDS -> 2 blocks/CU; VGPR ~116 (round-8 measured, no spill) at
// launch_bounds(256,2). Q pre-scaled by log2e/8; no running max.
// AO epilogue: coalesced 16-B stores via freed sPw (ran clean in round 8).
#define STAGE(kt, bK, bV) do { \
    _Pragma("unroll") \
    for (int p_ = 0; p_ < 4; ++p_) \
      gll16(kgb + (kt) * 8192 + p_ * 2048, (bK) + tid * 8 + p_ * 2048); \
    _Pragma("unroll") \
    for (int p_ = 0; p_ < 4; ++p_) \
      gll16(vgb + (kt) * 64 + p_ * 16384, (bV) + tid * 8 + p_ * 2048); \
  } while (0)

#define COMPUTE(bK, bV) do { \
  f32x4 s2[2][4] = {}; \
  _Pragma("unroll") \
  for (int ks = 0; ks < 4; ++ks) { \
    _Pragma("unroll") \
    for (int ni = 0; ni < 4; ++ni) { \
      const int row_ = ni * 16 + fr; \
      const s16x8 kf = *(const s16x8*)((bK) + row_ * 128 + ((ks * 32 + fq * 8) ^ ((row_ & 7) << 3))); \
      _Pragma("unroll") \
      for (int mi = 0; mi < 2; ++mi) \
        s2[mi][ni] = __builtin_amdgcn_mfma_f32_16x16x32_bf16(qf[mi][ks], kf, s2[mi][ni], 0, 0, 0); \
    } \
  } \
  _Pragma("unroll") \
  for (int mi = 0; mi < 2; ++mi) \
    _Pragma("unroll") \
    for (int r = 0; r < 4; ++r) { \
      float ps = 0.f; \
      _Pragma("unroll") \
      for (int ni = 0; ni < 4; ++ni) { \
        const float pe = __builtin_amdgcn_exp2f(s2[mi][ni][r]); \
        s2[mi][ni][r] = pe; ps += pe; \
      } \
      ps += __shfl_xor(ps, 1); ps += __shfl_xor(ps, 2); \
      ps += __shfl_xor(ps, 4); ps += __shfl_xor(ps, 8); \
      lrow[mi][r] += ps; \
    } \
  _Pragma("unroll") \
  for (int mi = 0; mi < 2; ++mi) \
    _Pragma("unroll") \
    for (int ni = 0; ni < 4; ++ni) \
      _Pragma("unroll") \
      for (int r = 0; r < 4; ++r) { \
        const int rp = mi * 16 + fq * 4 + r; \
        sPw[rp * 64 + ((ni * 16 + fr) ^ ((rp & 7) << 3))] = __float2bfloat16(s2[mi][ni][r]); \
      } \
  _Pragma("unroll") \
  for (int ks = 0; ks < 2; ++ks) { \
    s16x8 pf[2]; \
    _Pragma("unroll") \
    for (int mi = 0; mi < 2; ++mi) { \
      const int row_ = mi * 16 + fr; \
      pf[mi] = *(const s16x8*)(sPw + row_ * 64 + ((ks * 32 + fq * 8) ^ ((row_ & 7) << 3))); \
    } \
    _Pragma("unroll") \
    for (int nj = 0; nj < 8; ++nj) { \
      const int row_ = nj * 16 + fr; \
      const s16x8 vf = *(const s16x8*)((bV) + row_ * 64 + ((ks * 32 + fq * 8) ^ ((row_ & 7) << 3))); \
      _Pragma("unroll") \
      for (int mi = 0; mi < 2; ++mi) \
        o[mi][nj] = __builtin_amdgcn_mfma_f32_16x16x32_bf16(pf[mi], vf, o[mi][nj], 0, 0, 0); \
    } \
  } \
} while (0)

__global__ __launch_bounds__(256, 2) void attn_kernel(const bf16* __restrict__ Q,
                                                      const bf16* __restrict__ K,
                                                      const bf16* __restrict__ Vt,
                                                      bf16* __restrict__ AO) {
  __shared__ alignas(16) bf16 lds[40960];   // 80 KiB exactly -> 2 blocks/CU
  bf16* const ldsK0 = lds;                  // [64][128]
  bf16* const ldsV0 = lds + 8192;           // [128][64]
  bf16* const ldsK1 = lds + 16384;
  bf16* const ldsV1 = lds + 24576;
  bf16* const sP    = lds + 32768;          // 4 waves x [32][64]
  const int tid = threadIdx.x;
  const int w = tid >> 6, ln = tid & 63;
  const int fr = ln & 15, fq = ln >> 4;
  const int lg = (blockIdx.x & 7) * 128 + (blockIdx.x >> 3);
  const int bh = lg >> 2;
  const int q0 = (lg & 3) * 128;
  const long base = (long)bh << 16;         // bh * 512 * 128
  bf16* const sPw = sP + w * 2048;

  // thread-constant staging source bases (inverse-swizzled global addresses)
  const int kr0 = tid >> 4, kc = tid & 15;          // K/Q chunk coords
  const int vr0 = tid >> 3, vc = tid & 7;           // V^T chunk coords
  const bf16* const kgb = K + base + kr0 * 128 + ((kc ^ (kr0 & 7)) * 8);
  const bf16* const vgb = Vt + base + (long)vr0 * 512 + ((vc ^ (vr0 & 7)) * 8);

  // --- stage Q tile (128x128) swizzled into lds[0..16383], read fragments
  {
    const bf16* const qgb = Q + base + (long)q0 * 128 + kr0 * 128 + ((kc ^ (kr0 & 7)) * 8);
#pragma unroll
    for (int p = 0; p < 8; ++p)
      gll16(qgb + p * 2048, lds + tid * 8 + p * 2048);
  }
  __syncthreads();   // drains vmcnt(0): Q landed for all waves
  s16x8 qf[2][4];
#pragma unroll
  for (int mi = 0; mi < 2; ++mi) {
    const int row = w * 32 + mi * 16 + fr;
#pragma unroll
    for (int ks = 0; ks < 4; ++ks)
      qf[mi][ks] = *(const s16x8*)(lds + row * 128 + ((ks * 32 + fq * 8) ^ ((row & 7) << 3)));
  }
  __syncthreads();   // drains lgkm: Q region free for tile0

  f32x4 o[2][8] = {};
  float lrow[2][4] = {};

  STAGE(0, ldsK0, ldsV0);
  STAGE(1, ldsK1, ldsV1);

  for (int kt = 0; kt < 7; ++kt) {
    const bf16* bK = (kt & 1) ? ldsK1 : ldsK0;
    const bf16* bV = (kt & 1) ? ldsV1 : ldsV0;
    asm volatile("s_waitcnt vmcnt(8)" ::: "memory");   // tile kt landed; kt+1 in flight
    __builtin_amdgcn_sched_barrier(0);
    __builtin_amdgcn_s_barrier();
    COMPUTE(bK, bV);
    asm volatile("s_waitcnt lgkmcnt(0)" ::: "memory"); // my LDS reads complete
    __builtin_amdgcn_sched_barrier(0);
    __builtin_amdgcn_s_barrier();                      // everyone done reading buf
    if (kt < 6) STAGE(kt + 2, (bf16*)bK, (bf16*)bV);   // overwrite current buf
  }
  asm volatile("s_waitcnt vmcnt(0)" ::: "memory");
  __builtin_amdgcn_sched_barrier(0);
  __builtin_amdgcn_s_barrier();
  COMPUTE(ldsK1, ldsV1);   // kt = 7

  // --- epilogue: O /= l; coalesced AO writes via freed sPw (wave-private) ---
  const int b = bh >> 3, h = bh & 7;
  float rl[2][4];
#pragma unroll
  for (int mi = 0; mi < 2; ++mi)
#pragma unroll
    for (int r = 0; r < 4; ++r) rl[mi][r] = 1.f / lrow[mi][r];
#pragma unroll
  for (int hh = 0; hh < 2; ++hh) {
#pragma unroll
    for (int mi = 0; mi < 2; ++mi)
#pragma unroll
      for (int nj4 = 0; nj4 < 4; ++nj4)
#pragma unroll
        for (int r = 0; r < 4; ++r) {
          const int rp = mi * 16 + fq * 4 + r;
          sPw[rp * 64 + ((nj4 * 16 + fr) ^ ((rp & 7) << 3))] =
              __float2bfloat16(o[mi][hh * 4 + nj4][r] * rl[mi][r]);
        }
#pragma unroll
    for (int pp = 0; pp < 4; ++pp) {
      const int rr = pp * 8 + (ln >> 3);
      const s16x8 v = *(const s16x8*)(sPw + rr * 64 + (((ln & 7) * 8) ^ ((rr & 7) << 3)));
      *(s16x8*)(AO + (((long)(b * 512 + q0 + w * 32 + rr)) << 10) + h * 128 + hh * 64 + (ln & 7) * 8) = v;
    }
  }
}

// ---------------- launch ----------------
extern "C" void kernel_launch(void* const* d_in, const int* in_sizes, int n_in,
                              void* d_out, int out_size, void* d_ws, size_t ws_size,
                              hipStream_t stream) {
  const float* xf = (const float*)d_in[0];
  const float* xs = (const float*)d_in[1];
  // weight order in WW: 0=wq1,1=wk1,2=wv1,3=wq2,4=wk2,5=wv2,6=wo1,7=wo2
  const float* w_f[8] = { (const float*)d_in[2], (const float*)d_in[4], (const float*)d_in[6],
                          (const float*)d_in[8], (const float*)d_in[10], (const float*)d_in[12],
                          (const float*)d_in[14], (const float*)d_in[16] };

  bf16* ws = (bf16*)d_ws;
  bf16* XF = ws;                       // 8,388,608 bf16
  bf16* XS = ws + 8388608;             // 8,388,608
  bf16* WW = ws + 16777216;            // 8 x 262,144
  bf16* Qb = ws + 18874368;            // 16,777,216 each
  bf16* Kb = Qb + 16777216;
  bf16* Vb = Kb + 16777216;            // V^T layout (bh, d, t)
  bf16* AO = ws;                       // reuse XF+XS region

  ConvParams cp;
  cp.j[0] = { xf, XF, 2097152, 0 };
  cp.j[1] = { xs, XS, 2097152, 0 };
  for (int i = 0; i < 8; ++i) cp.j[2 + i] = { w_f[i], WW + i * 262144, 65536, 0 };
  convert_kernel<<<dim3(512, 1, 10), 256, 0, stream>>>(cp);

  const float qsc = 0.125f * 1.44269504088896f;   // fold log2(e) so attn uses exp2
  GemmParams gp;
  gp.s[0] = { XF, WW + 0 * 262144, (const float*)d_in[3],  Qb, nullptr, 512, 0,  qsc, 0 };
  gp.s[1] = { XS, WW + 3 * 262144, (const float*)d_in[9],  Qb, nullptr, 512, 64, qsc, 0 };
  gp.s[2] = { XF, WW + 1 * 262144, (const float*)d_in[5],  Kb, nullptr, 512, 0,  1.f, 0 };
  gp.s[3] = { XS, WW + 4 * 262144, (const float*)d_in[11], Kb, nullptr, 512, 64, 1.f, 0 };
  gp.s[4] = { XF, WW + 2 * 262144, (const float*)d_in[7],  Vb, nullptr, 512, 0,  1.f, 2 };
  gp.s[5] = { XS, WW + 5 * 262144, (const float*)d_in[13], Vb, nullptr, 512, 64, 1.f, 2 };
  gemm_kernel<<<dim3(128, 4, 6), 256, 0, stream>>>(gp);

  attn_kernel<<<dim3(1024), 256, 0, stream>>>(Qb, Kb, Vb, AO);

  float* out = (float*)d_out;
  GemmParams op;
  op.s[0] = { AO,       WW + 6 * 262144, (const float*)d_in[15], nullptr, out,           1024, 0, 1.f, 1 };
  op.s[1] = { AO + 512, WW + 7 * 262144, (const float*)d_in[17], nullptr, out + 8388608, 1024, 0, 1.f, 1 };
  op.s[2] = op.s[0]; op.s[3] = op.s[0]; op.s[4] = op.s[0]; op.s[5] = op.s[0];
  gemm_kernel<<<dim3(128, 4, 2), 256, 0, stream>>>(op);
}

// Round 13
// 154.303 us; speedup vs baseline: 2.2593x; 1.0591x over previous
//
#include <hip/hip_runtime.h>
#include <hip/hip_bf16.h>
#include <stdint.h>

typedef __hip_bfloat16 bf16;
using f32x4 = __attribute__((ext_vector_type(4))) float;
using s16x8 = __attribute__((ext_vector_type(8))) short;

typedef __attribute__((address_space(1))) unsigned int gu32;
typedef __attribute__((address_space(3))) unsigned int lu32;

__device__ __forceinline__ void gll16(const void* g, void* l) {
  __builtin_amdgcn_global_load_lds((const gu32*)g, (lu32*)l, 16, 0, 0);
}

// ---------------- convert f32 -> bf16 ----------------
struct ConvJob { const float* src; bf16* dst; int n4; int pad; };
struct ConvParams { ConvJob j[10]; };
struct alignas(8) Bf4 { bf16 v[4]; };

__global__ void convert_kernel(ConvParams p) {
  ConvJob jb = p.j[blockIdx.z];
  int stride = gridDim.x * blockDim.x;
  for (int i = blockIdx.x * blockDim.x + threadIdx.x; i < jb.n4; i += stride) {
    float4 v = ((const float4*)jb.src)[i];
    Bf4 o;
    o.v[0] = __float2bfloat16(v.x);
    o.v[1] = __float2bfloat16(v.y);
    o.v[2] = __float2bfloat16(v.z);
    o.v[3] = __float2bfloat16(v.w);
    ((Bf4*)jb.dst)[i] = o;
  }
}

// ---------------- GEMM: C = A(MxK) @ W(NxK)^T + bias ----------------
// Round-12 verified: single-buffer 32 KiB K-loop, 4 blocks/CU at
// __launch_bounds__(256,4) (VGPR ~60 + AGPR 64 fits 128 budget). K always
// 512 (8 tiles); lda is only A's row stride. Coalesced two-pass epilogue
// in wave-private 4.5 KiB LDS buffer. DO NOT TOUCH — verified best.
struct GemmSlice {
  const bf16* A; const bf16* W; const float* bias;
  bf16* dstQ; float* dstF;
  long lda; int dhalf; float scale; int mode;
};
struct GemmParams { GemmSlice s[6]; };

// per wave: 4 A-loads + 4 B-loads = 8 gll16 per tile
#define GSTAGE(kb) do { \
    _Pragma("unroll") \
    for (int i_ = 0; i_ < 4; ++i_) { \
      const int r0_ = w * 32 + i_ * 8; \
      gll16(Abase + (long)r0_ * lda + (kb) * 64, sA + r0_ * 64); \
      gll16(Wbase + (long)r0_ * 512 + (kb) * 64, sB + r0_ * 64); \
    } \
  } while (0)

#define GCOMPUTE() do { \
  _Pragma("unroll") \
  for (int ks = 0; ks < 2; ++ks) { \
    s16x8 af[4], bg[4]; \
    _Pragma("unroll") \
    for (int mi = 0; mi < 4; ++mi) { \
      const int row_ = wm + mi * 16 + fr; \
      af[mi] = *(const s16x8*)(sA + row_ * 64 + ((ks * 32 + fq * 8) ^ ((row_ & 7) << 3))); \
    } \
    _Pragma("unroll") \
    for (int ni = 0; ni < 4; ++ni) { \
      const int row_ = wn + ni * 16 + fr; \
      bg[ni] = *(const s16x8*)(sB + row_ * 64 + ((ks * 32 + fq * 8) ^ ((row_ & 7) << 3))); \
    } \
    __builtin_amdgcn_s_setprio(1); \
    _Pragma("unroll") \
    for (int mi = 0; mi < 4; ++mi) \
      _Pragma("unroll") \
      for (int ni = 0; ni < 4; ++ni) \
        acc[mi][ni] = __builtin_amdgcn_mfma_f32_16x16x32_bf16(af[mi], bg[ni], acc[mi][ni], 0, 0, 0); \
    __builtin_amdgcn_s_setprio(0); \
  } \
} while (0)

__global__ __launch_bounds__(256, 4) void gemm_kernel(GemmParams p) {
  __shared__ alignas(16) bf16 lds[16384];   // 32 KiB: sA @0, sB @8192
  bf16* const sA = lds;
  bf16* const sB = lds + 8192;
  const GemmSlice sl = p.s[blockIdx.z];
  const long lda = sl.lda;
  const int tid = threadIdx.x;
  const int w = tid >> 6, ln = tid & 63;
  const int gm0 = blockIdx.x * 128;
  const int gn0 = blockIdx.y * 128;
  const int arow = ln >> 3;
  const int acolS = ((ln & 7) ^ (ln >> 3)) * 8;   // inverse-swizzled source column
  const int wm = (w >> 1) * 64, wn = (w & 1) * 64;
  const int fr = ln & 15, fq = ln >> 4;
  const bf16* const Abase = sl.A + (long)(gm0 + arow) * lda + acolS;
  const bf16* const Wbase = sl.W + (long)(gn0 + arow) * 512 + acolS;
  f32x4 acc[4][4] = {};

  for (int kb = 0; kb < 8; ++kb) {   // K = 512 always (lda is only A's row stride)
    GSTAGE(kb);
    __syncthreads();   // drains vmcnt(0): tile landed
    GCOMPUTE();
    __syncthreads();   // all reads done before next-tile overwrite
  }

  // --- coalesced epilogue: wave-PRIVATE 32x72 buffer, two passes, no barriers ---
  bf16* const eW = lds + w * 2304;          // 4608 B/wave, 18,432 B total
  if (sl.mode == 0) {
    const int col0 = gn0 + wn;              // 64-aligned -> single head h
    const int h = col0 >> 6;
    const int bh = ((gm0 >> 9) << 3) + h;
    const int tb = (gm0 & 511) + wm;
#pragma unroll
    for (int ps = 0; ps < 2; ++ps) {        // rows mi = 2ps, 2ps+1
#pragma unroll
      for (int mi2 = 0; mi2 < 2; ++mi2) {
        const int mi = ps * 2 + mi2;
#pragma unroll
        for (int ni = 0; ni < 4; ++ni) {
          const float bia = sl.bias[col0 + ni * 16 + fr];
#pragma unroll
          for (int r = 0; r < 4; ++r)
            eW[(mi2 * 16 + fq * 4 + r) * 72 + ni * 16 + fr] =
                __float2bfloat16((acc[mi][ni][r] + bia) * sl.scale);
        }
      }
#pragma unroll
      for (int pp = 0; pp < 4; ++pp) {
        const int rr = pp * 8 + (ln >> 3);  // 0..31
        const s16x8 v = *(const s16x8*)(eW + rr * 72 + (ln & 7) * 8);
        *(s16x8*)(sl.dstQ + (((long)bh * 512 + tb + ps * 32 + rr) << 7) + sl.dhalf + (ln & 7) * 8) = v;
      }
    }
  } else if (sl.mode == 2) {
    const int col0 = gn0 + wn;
    const int h = col0 >> 6;
    const int bh = ((gm0 >> 9) << 3) + h;
    const int tb = (gm0 & 511) + wm;
    // eW layout per pass: [dd' 0..31][t 0..63 pad 72]
#pragma unroll
    for (int ps = 0; ps < 2; ++ps) {        // dd halves: ni = 2ps, 2ps+1
#pragma unroll
      for (int ni2 = 0; ni2 < 2; ++ni2) {
        const int ni = ps * 2 + ni2;
        const float bia = sl.bias[col0 + ni * 16 + fr];
#pragma unroll
        for (int mi = 0; mi < 4; ++mi) {
          Bf4 o;
#pragma unroll
          for (int r = 0; r < 4; ++r) o.v[r] = __float2bfloat16(acc[mi][ni][r] + bia);
          *(Bf4*)(eW + (ni2 * 16 + fr) * 72 + mi * 16 + fq * 4) = o;
        }
      }
#pragma unroll
      for (int pp = 0; pp < 4; ++pp) {
        const int rr = pp * 8 + (ln >> 3);  // dd' 0..31
        const s16x8 v = *(const s16x8*)(eW + rr * 72 + (ln & 7) * 8);
        *(s16x8*)(sl.dstQ + (((long)bh * 128 + sl.dhalf + ps * 32 + rr) << 9) + tb + (ln & 7) * 8) = v;
      }
    }
  } else {
#pragma unroll
    for (int mi = 0; mi < 4; ++mi)
#pragma unroll
      for (int ni = 0; ni < 4; ++ni) {
        const int col = gn0 + wn + ni * 16 + fr;
        const float bia = sl.bias[col];
#pragma unroll
        for (int r = 0; r < 4; ++r) {
          const int row = gm0 + wm + mi * 16 + fq * 4 + r;
          sl.dstF[(long)row * 512 + col] = acc[mi][ni][r] + bia;
        }
      }
  }
}

// ---------------- flash attention (round-6 structure; MFMA row-sum) ----------------
// 4 waves x 32 q-rows, KVBLK=64, dbuf gll16 + counted vmcnt(8), T2 swizzle,
// 80 KiB LDS -> 2 blocks/CU. Q pre-scaled by log2e/8; no running max.
// ROUND-13 CHANGE: the 32-shfl_xor cross-lane row-sum (latency-chained,
// VALUBusy>MfmaUtil) is replaced by row-sum ON THE MATRIX PIPE:
// lracc[mi] = mfma(pf[mi], ones, lracc[mi]) per ks -> D[fq*4+r][fr] =
// sum_k P[q][k], exactly the per-lane lrow mapping, f32-accumulated.
// 4 extra MFMA/tile replace 32 shfl + 16 add. Sum is over the SAME bf16 P
// used in PV (more consistent). AO epilogue: coalesced via freed sPw.
#define STAGE(kt, bK, bV) do { \
    _Pragma("unroll") \
    for (int p_ = 0; p_ < 4; ++p_) \
      gll16(kgb + (kt) * 8192 + p_ * 2048, (bK) + tid * 8 + p_ * 2048); \
    _Pragma("unroll") \
    for (int p_ = 0; p_ < 4; ++p_) \
      gll16(vgb + (kt) * 64 + p_ * 16384, (bV) + tid * 8 + p_ * 2048); \
  } while (0)

#define COMPUTE(bK, bV) do { \
  f32x4 s2[2][4] = {}; \
  _Pragma("unroll") \
  for (int ks = 0; ks < 4; ++ks) { \
    _Pragma("unroll") \
    for (int ni = 0; ni < 4; ++ni) { \
      const int row_ = ni * 16 + fr; \
      const s16x8 kf = *(const s16x8*)((bK) + row_ * 128 + ((ks * 32 + fq * 8) ^ ((row_ & 7) << 3))); \
      _Pragma("unroll") \
      for (int mi = 0; mi < 2; ++mi) \
        s2[mi][ni] = __builtin_amdgcn_mfma_f32_16x16x32_bf16(qf[mi][ks], kf, s2[mi][ni], 0, 0, 0); \
    } \
  } \
  _Pragma("unroll") \
  for (int mi = 0; mi < 2; ++mi) \
    _Pragma("unroll") \
    for (int ni = 0; ni < 4; ++ni) \
      _Pragma("unroll") \
      for (int r = 0; r < 4; ++r) { \
        const int rp = mi * 16 + fq * 4 + r; \
        sPw[rp * 64 + ((ni * 16 + fr) ^ ((rp & 7) << 3))] = \
            __float2bfloat16(__builtin_amdgcn_exp2f(s2[mi][ni][r])); \
      } \
  _Pragma("unroll") \
  for (int ks = 0; ks < 2; ++ks) { \
    s16x8 pf[2]; \
    _Pragma("unroll") \
    for (int mi = 0; mi < 2; ++mi) { \
      const int row_ = mi * 16 + fr; \
      pf[mi] = *(const s16x8*)(sPw + row_ * 64 + ((ks * 32 + fq * 8) ^ ((row_ & 7) << 3))); \
      lracc[mi] = __builtin_amdgcn_mfma_f32_16x16x32_bf16(pf[mi], onesf, lracc[mi], 0, 0, 0); \
    } \
    _Pragma("unroll") \
    for (int nj = 0; nj < 8; ++nj) { \
      const int row_ = nj * 16 + fr; \
      const s16x8 vf = *(const s16x8*)((bV) + row_ * 64 + ((ks * 32 + fq * 8) ^ ((row_ & 7) << 3))); \
      _Pragma("unroll") \
      for (int mi = 0; mi < 2; ++mi) \
        o[mi][nj] = __builtin_amdgcn_mfma_f32_16x16x32_bf16(pf[mi], vf, o[mi][nj], 0, 0, 0); \
    } \
  } \
} while (0)

__global__ __launch_bounds__(256, 2) void attn_kernel(const bf16* __restrict__ Q,
                                                      const bf16* __restrict__ K,
                                                      const bf16* __restrict__ Vt,
                                                      bf16* __restrict__ AO) {
  __shared__ alignas(16) bf16 lds[40960];   // 80 KiB exactly -> 2 blocks/CU
  bf16* const ldsK0 = lds;                  // [64][128]
  bf16* const ldsV0 = lds + 8192;           // [128][64]
  bf16* const ldsK1 = lds + 16384;
  bf16* const ldsV1 = lds + 24576;
  bf16* const sP    = lds + 32768;          // 4 waves x [32][64]
  const int tid = threadIdx.x;
  const int w = tid >> 6, ln = tid & 63;
  const int fr = ln & 15, fq = ln >> 4;
  const int lg = (blockIdx.x & 7) * 128 + (blockIdx.x >> 3);
  const int bh = lg >> 2;
  const int q0 = (lg & 3) * 128;
  const long base = (long)bh << 16;         // bh * 512 * 128
  bf16* const sPw = sP + w * 2048;

  // thread-constant staging source bases (inverse-swizzled global addresses)
  const int kr0 = tid >> 4, kc = tid & 15;          // K/Q chunk coords
  const int vr0 = tid >> 3, vc = tid & 7;           // V^T chunk coords
  const bf16* const kgb = K + base + kr0 * 128 + ((kc ^ (kr0 & 7)) * 8);
  const bf16* const vgb = Vt + base + (long)vr0 * 512 + ((vc ^ (vr0 & 7)) * 8);

  // --- stage Q tile (128x128) swizzled into lds[0..16383], read fragments
  {
    const bf16* const qgb = Q + base + (long)q0 * 128 + kr0 * 128 + ((kc ^ (kr0 & 7)) * 8);
#pragma unroll
    for (int p = 0; p < 8; ++p)
      gll16(qgb + p * 2048, lds + tid * 8 + p * 2048);
  }
  __syncthreads();   // drains vmcnt(0): Q landed for all waves
  s16x8 qf[2][4];
#pragma unroll
  for (int mi = 0; mi < 2; ++mi) {
    const int row = w * 32 + mi * 16 + fr;
#pragma unroll
    for (int ks = 0; ks < 4; ++ks)
      qf[mi][ks] = *(const s16x8*)(lds + row * 128 + ((ks * 32 + fq * 8) ^ ((row & 7) << 3)));
  }
  __syncthreads();   // drains lgkm: Q region free for tile0

  f32x4 o[2][8] = {};
  f32x4 lracc[2] = {};
  const short one_bf16 = (short)0x3F80;     // bf16 1.0
  const s16x8 onesf = { one_bf16, one_bf16, one_bf16, one_bf16,
                        one_bf16, one_bf16, one_bf16, one_bf16 };

  STAGE(0, ldsK0, ldsV0);
  STAGE(1, ldsK1, ldsV1);

  for (int kt = 0; kt < 7; ++kt) {
    const bf16* bK = (kt & 1) ? ldsK1 : ldsK0;
    const bf16* bV = (kt & 1) ? ldsV1 : ldsV0;
    asm volatile("s_waitcnt vmcnt(8)" ::: "memory");   // tile kt landed; kt+1 in flight
    __builtin_amdgcn_sched_barrier(0);
    __builtin_amdgcn_s_barrier();
    COMPUTE(bK, bV);
    asm volatile("s_waitcnt lgkmcnt(0)" ::: "memory"); // my LDS reads complete
    __builtin_amdgcn_sched_barrier(0);
    __builtin_amdgcn_s_barrier();                      // everyone done reading buf
    if (kt < 6) STAGE(kt + 2, (bf16*)bK, (bf16*)bV);   // overwrite current buf
  }
  asm volatile("s_waitcnt vmcnt(0)" ::: "memory");
  __builtin_amdgcn_sched_barrier(0);
  __builtin_amdgcn_s_barrier();
  COMPUTE(ldsK1, ldsV1);   // kt = 7

  // --- epilogue: O /= l; coalesced AO writes via freed sPw (wave-private) ---
  const int b = bh >> 3, h = bh & 7;
  float rl[2][4];
#pragma unroll
  for (int mi = 0; mi < 2; ++mi)
#pragma unroll
    for (int r = 0; r < 4; ++r) rl[mi][r] = 1.f / lracc[mi][r];
#pragma unroll
  for (int hh = 0; hh < 2; ++hh) {
#pragma unroll
    for (int mi = 0; mi < 2; ++mi)
#pragma unroll
      for (int nj4 = 0; nj4 < 4; ++nj4)
#pragma unroll
        for (int r = 0; r < 4; ++r) {
          const int rp = mi * 16 + fq * 4 + r;
          sPw[rp * 64 + ((nj4 * 16 + fr) ^ ((rp & 7) << 3))] =
              __float2bfloat16(o[mi][hh * 4 + nj4][r] * rl[mi][r]);
        }
#pragma unroll
    for (int pp = 0; pp < 4; ++pp) {
      const int rr = pp * 8 + (ln >> 3);
      const s16x8 v = *(const s16x8*)(sPw + rr * 64 + (((ln & 7) * 8) ^ ((rr & 7) << 3)));
      *(s16x8*)(AO + (((long)(b * 512 + q0 + w * 32 + rr)) << 10) + h * 128 + hh * 64 + (ln & 7) * 8) = v;
    }
  }
}

// ---------------- launch ----------------
extern "C" void kernel_launch(void* const* d_in, const int* in_sizes, int n_in,
                              void* d_out, int out_size, void* d_ws, size_t ws_size,
                              hipStream_t stream) {
  const float* xf = (const float*)d_in[0];
  const float* xs = (const float*)d_in[1];
  // weight order in WW: 0=wq1,1=wk1,2=wv1,3=wq2,4=wk2,5=wv2,6=wo1,7=wo2
  const float* w_f[8] = { (const float*)d_in[2], (const float*)d_in[4], (const float*)d_in[6],
                          (const float*)d_in[8], (const float*)d_in[10], (const float*)d_in[12],
                          (const float*)d_in[14], (const float*)d_in[16] };

  bf16* ws = (bf16*)d_ws;
  bf16* XF = ws;                       // 8,388,608 bf16
  bf16* XS = ws + 8388608;             // 8,388,608
  bf16* WW = ws + 16777216;            // 8 x 262,144
  bf16* Qb = ws + 18874368;            // 16,777,216 each
  bf16* Kb = Qb + 16777216;
  bf16* Vb = Kb + 16777216;            // V^T layout (bh, d, t)
  bf16* AO = ws;                       // reuse XF+XS region

  ConvParams cp;
  cp.j[0] = { xf, XF, 2097152, 0 };
  cp.j[1] = { xs, XS, 2097152, 0 };
  for (int i = 0; i < 8; ++i) cp.j[2 + i] = { w_f[i], WW + i * 262144, 65536, 0 };
  convert_kernel<<<dim3(512, 1, 10), 256, 0, stream>>>(cp);

  const float qsc = 0.125f * 1.44269504088896f;   // fold log2(e) so attn uses exp2
  GemmParams gp;
  gp.s[0] = { XF, WW + 0 * 262144, (const float*)d_in[3],  Qb, nullptr, 512, 0,  qsc, 0 };
  gp.s[1] = { XS, WW + 3 * 262144, (const float*)d_in[9],  Qb, nullptr, 512, 64, qsc, 0 };
  gp.s[2] = { XF, WW + 1 * 262144, (const float*)d_in[5],  Kb, nullptr, 512, 0,  1.f, 0 };
  gp.s[3] = { XS, WW + 4 * 262144, (const float*)d_in[11], Kb, nullptr, 512, 64, 1.f, 0 };
  gp.s[4] = { XF, WW + 2 * 262144, (const float*)d_in[7],  Vb, nullptr, 512, 0,  1.f, 2 };
  gp.s[5] = { XS, WW + 5 * 262144, (const float*)d_in[13], Vb, nullptr, 512, 64, 1.f, 2 };
  gemm_kernel<<<dim3(128, 4, 6), 256, 0, stream>>>(gp);

  attn_kernel<<<dim3(1024), 256, 0, stream>>>(Qb, Kb, Vb, AO);

  float* out = (float*)d_out;
  GemmParams op;
  op.s[0] = { AO,       WW + 6 * 262144, (const float*)d_in[15], nullptr, out,           1024, 0, 1.f, 1 };
  op.s[1] = { AO + 512, WW + 7 * 262144, (const float*)d_in[17], nullptr, out + 8388608, 1024, 0, 1.f, 1 };
  op.s[2] = op.s[0]; op.s[3] = op.s[0]; op.s[4] = op.s[0]; op.s[5] = op.s[0];
  gemm_kernel<<<dim3(128, 4, 2), 256, 0, stream>>>(op);
}